// Round 1
// baseline (161.588 us; speedup 1.0000x reference)
//
#include <hip/hip_runtime.h>
#include <stdint.h>

// HolographicFMLayer: out[b, p=(i,j), n] = sum_m X[b,i,m] * X[b,j,(n-m) & 63]
// for all 276 pairs i<j of 24 fields, dim 64, batch 2048. fp32 in/out.
//
// Strategy: per batch, per j: Out_j = Xrows @ Circulant(x_j) as bf16 MFMA
// (16x16x32). Circulant is never materialized: B fragments are contiguous
// 8-element windows of a reversed-doubled array r_j[u] = x_j[(-u)&63],
// gathered with aligned ds_read_b64 x3 + branchless 64-bit funnel shift.
// A fragments (X rows, bf16) are loop-invariant per batch -> registers.

typedef __bf16 bf16x8 __attribute__((ext_vector_type(8)));
typedef float  f32x4  __attribute__((ext_vector_type(4)));

#define NF       24
#define DIM      64
#define NPAIR    276
// r_j rows: 128 bf16 used (256 B) + 8 B pad so the speculative 3rd ds_read_b64
// never crosses a row; 264 keeps 8 B alignment.
#define RSTRIDE  264
#define XB_OFF   (NF * RSTRIDE)          // 6336 B, 16B-aligned
#define XB_STRIDE 72                      // elems (144 B) -> aligned b128 rows, conflict-spread
#define LDS_BYTES (XB_OFF + 32 * XB_STRIDE * 2)   // 6336 + 4608 = 10944 B

__global__ __launch_bounds__(256)
void holo_fm_kernel(const float* __restrict__ in, float* __restrict__ out)
{
    __shared__ __align__(16) unsigned char lds[LDS_BYTES];
    __bf16* xb = (__bf16*)(lds + XB_OFF);

    const int tid = threadIdx.x;
    const int b   = blockIdx.x;
    const float* xin = in + (size_t)b * (NF * DIM);

    // Zero A-pad rows 24..31 (i-tile 1 reads them; results masked but keep finite).
    for (int e = tid; e < (32 - NF) * XB_STRIDE; e += 256)
        xb[NF * XB_STRIDE + e] = (__bf16)0.0f;

    // Stage: xb[i][m] = bf16(X[i][m]);  r_i[u] = bf16(X[i][(-u)&63]), doubled.
    for (int e = tid; e < NF * DIM; e += 256) {
        int i = e >> 6, m = e & 63;
        __bf16 v = (__bf16)xin[e];
        xb[i * XB_STRIDE + m] = v;
        __bf16* rj = (__bf16*)(lds + i * RSTRIDE);
        int u0 = (64 - m) & 63;
        rj[u0]      = v;
        rj[u0 + 64] = v;
    }
    __syncthreads();

    const int lane = tid & 63;
    const int wave = tid >> 6;
    const int ln   = lane & 15;   // A row within tile / B-C col within tile
    const int q    = lane >> 4;   // k-quad for A/B; row-quad for C/D

    // A fragments: A[m=ln][k=q*8+t], k-block ks*32. it = i-tile (rows it*16..+15).
    bf16x8 afrag[2][2];
    #pragma unroll
    for (int it = 0; it < 2; ++it)
        #pragma unroll
        for (int ks = 0; ks < 2; ++ks)
            afrag[it][ks] = *(const bf16x8*)(xb + (it * 16 + ln) * XB_STRIDE + ks * 32 + q * 8);

    // Each wave takes j = wave+1, wave+5, ...
    for (int j = wave + 1; j < NF; j += 4) {
        const uint64_t* rj = (const uint64_t*)(lds + j * RSTRIDE);
        #pragma unroll
        for (int nt = 0; nt < 4; ++nt) {
            const int n = nt * 16 + ln;
            bf16x8 bfr[2];
            #pragma unroll
            for (int ks = 0; ks < 2; ++ks) {
                // B[k][n] = x_j[(n-k)&63] = r_j[64 + k - n]; window start:
                int ob = 2 * (64 + 32 * ks + 8 * q - n);   // byte offset, in [2,240]
                int dw = ob >> 3;                           // u64 index
                int sh = (ob & 7) * 8;                      // 0/16/32/48 bits
                uint64_t w0 = rj[dw], w1 = rj[dw + 1], w2 = rj[dw + 2];
                // branchless funnel (safe at sh==0: (w<<1)<<63 contributes 0)
                uint64_t lo = (w0 >> sh) | ((w1 << 1) << (63 - sh));
                uint64_t hi = (w1 >> sh) | ((w2 << 1) << (63 - sh));
                union { uint64_t u[2]; bf16x8 v; } cv;
                cv.u[0] = lo; cv.u[1] = hi;
                bfr[ks] = cv.v;
            }

            float* ob0 = out + ((size_t)b * NPAIR) * DIM + n;

            f32x4 c0 = {0.f, 0.f, 0.f, 0.f};
            c0 = __builtin_amdgcn_mfma_f32_16x16x32_bf16(afrag[0][0], bfr[0], c0, 0, 0, 0);
            c0 = __builtin_amdgcn_mfma_f32_16x16x32_bf16(afrag[0][1], bfr[1], c0, 0, 0, 0);
            #pragma unroll
            for (int r = 0; r < 4; ++r) {
                int i = 4 * q + r;                 // C/D: row = 4*quad + reg
                if (i < j) {
                    int pidx = 23 * i - (i * (i - 1)) / 2 + (j - i - 1);
                    ob0[(size_t)pidx * DIM] = c0[r];
                }
            }

            if (j > 16) {                          // i-tile 1: rows 16..23
                f32x4 c1 = {0.f, 0.f, 0.f, 0.f};
                c1 = __builtin_amdgcn_mfma_f32_16x16x32_bf16(afrag[1][0], bfr[0], c1, 0, 0, 0);
                c1 = __builtin_amdgcn_mfma_f32_16x16x32_bf16(afrag[1][1], bfr[1], c1, 0, 0, 0);
                #pragma unroll
                for (int r = 0; r < 4; ++r) {
                    int i = 16 + 4 * q + r;
                    if (i < j) {
                        int pidx = 23 * i - (i * (i - 1)) / 2 + (j - i - 1);
                        ob0[(size_t)pidx * DIM] = c1[r];
                    }
                }
            }
        }
    }
}

extern "C" void kernel_launch(void* const* d_in, const int* in_sizes, int n_in,
                              void* d_out, int out_size, void* d_ws, size_t ws_size,
                              hipStream_t stream)
{
    const float* in  = (const float*)d_in[0];
    float*       out = (float*)d_out;
    const int batches = in_sizes[0] / (NF * DIM);   // 2048
    holo_fm_kernel<<<dim3(batches), dim3(256), 0, stream>>>(in, out);
}

// Round 2
// 159.139 us; speedup vs baseline: 1.0154x; 1.0154x over previous
//
#include <hip/hip_runtime.h>
#include <stdint.h>

// HolographicFMLayer: out[b, p(i,j), n] = sum_m X[b,i,m] * X[b,j,(n-m)&63],
// pairs i<j of 24 fields, dim 64, batch 2048, fp32 in/out.
//
// R2 restructure: circular conv is commutative, so compute per-i the
// TRANSPOSED product D[n][j] = sum_k A[n][k] * B[k][j] with
//   A[n][k] = x_i[(n-k)&63]  (circulant windows from reversed-doubled r_i,
//                             funnel-shift gather; only 6 distinct windows
//                             cover all 8 (mt,ks) tiles since they depend on
//                             beta = 64+32ks-16mt in {16,32,48,64,80,96})
//   B[k][j] = X[j][k]        (contiguous-k fragments, loop-invariant/batch)
// MFMA C-layout (row=4q+r, col=ln) then gives each lane 4 CONSECUTIVE n at
// fixed j -> direct global_store_dwordx4; consecutive j -> consecutive pidx
// -> contiguous 256B output rows. No per-element pidx math, no LDS epilogue.

typedef __bf16 bf16x8 __attribute__((ext_vector_type(8)));
typedef float  f32x4  __attribute__((ext_vector_type(4)));

#define NF       24
#define DIM      64
#define NPAIR    276
// r_i rows: 128 bf16 (256 B) + 8 B pad so ds_read_b64 at dw+2 (word 32) is
// in-bounds; 264 B keeps 8 B alignment per row.
#define RSTRIDE  264
#define XB_OFF   (NF * RSTRIDE)           // 6336 B, 16B-aligned
#define XB_STRIDE 72                       // elems; 144 B rows, 16B-aligned
#define LDS_BYTES (XB_OFF + 32 * XB_STRIDE * 2)   // 6336 + 4608 = 10944 B

__global__ __launch_bounds__(256)
void holo_fm_kernel(const float* __restrict__ in, float* __restrict__ out)
{
    __shared__ __align__(16) unsigned char lds[LDS_BYTES];
    __bf16* xb = (__bf16*)(lds + XB_OFF);

    const int tid = threadIdx.x;
    const int b   = blockIdx.x;
    const float* xin = in + (size_t)b * (NF * DIM);

    // Zero B-pad rows 24..31 (jt=1 tile reads them; c there is masked).
    for (int e = tid; e < (32 - NF) * XB_STRIDE; e += 256)
        xb[NF * XB_STRIDE + e] = (__bf16)0.0f;

    // Stage: xb[j][k] = bf16(X[j][k]);  r_i[u] = bf16(X[i][(-u)&63]), doubled.
    for (int e = tid; e < NF * DIM; e += 256) {
        int f = e >> 6, m = e & 63;
        __bf16 v = (__bf16)xin[e];
        xb[f * XB_STRIDE + m] = v;
        __bf16* rr = (__bf16*)(lds + f * RSTRIDE);
        int u0 = (64 - m) & 63;
        rr[u0]      = v;
        rr[u0 + 64] = v;
    }
    __syncthreads();

    const int lane = tid & 63;
    const int wave = tid >> 6;
    const int ln   = lane & 15;   // B col j within tile / A row n within tile
    const int q    = lane >> 4;   // k-quad for A/B; n-row-quad for C/D

    // B fragments: B[k][j] = X[j][k]; lane holds k = 32ks + 8q + t, j-tile jt.
    // Loop-invariant over the whole batch.
    bf16x8 bfrag[2][2];
    #pragma unroll
    for (int jt = 0; jt < 2; ++jt)
        #pragma unroll
        for (int ks = 0; ks < 2; ++ks)
            bfrag[jt][ks] = *(const bf16x8*)(xb + (jt * 16 + ln) * XB_STRIDE + ks * 32 + q * 8);

    float* gbase = out + (size_t)b * NPAIR * DIM;

    // Each wave takes i = wave, wave+4, ... (i=23 has no pairs).
    for (int i = wave; i < NF - 1; i += 4) {
        const uint64_t* ri = (const uint64_t*)(lds + i * RSTRIDE);
        const int p0 = 23 * i - (i * (i - 1)) / 2;   // pidx of (i, i+1)

        // 6 distinct circulant A-windows: awin[w] covers beta = 16*(w+1).
        // A[n=16mt+ln][k=32ks+8q+t] = r_i[beta + 8q + t - ln], tile uses
        // awin[3 + 2*ks - mt].
        bf16x8 awin[6];
        #pragma unroll
        for (int w = 0; w < 6; ++w) {
            int ob = 2 * (16 * (w + 1) + 8 * q - ln);  // byte offset in [2,240]
            int dw = ob >> 3;
            int sh = (ob & 7) * 8;                      // 0/16/32/48 (lane-const)
            uint64_t w0 = ri[dw], w1 = ri[dw + 1], w2 = ri[dw + 2];
            uint64_t lo = (w0 >> sh) | ((w1 << 1) << (63 - sh));
            uint64_t hi = (w1 >> sh) | ((w2 << 1) << (63 - sh));
            union { uint64_t u[2]; bf16x8 v; } cv;
            cv.u[0] = lo; cv.u[1] = hi;
            awin[w] = cv.v;
        }

        const int jtlo = (i < 15) ? 0 : 1;   // jt=0 only has j>i lanes if i<15
        for (int jt = jtlo; jt < 2; ++jt) {
            const int j = 16 * jt + ln;
            const bool valid = (j > i) & (j < NF);
            float* orow = gbase + ((size_t)(p0 + j - i - 1)) * DIM + 4 * q;
            #pragma unroll
            for (int mt = 0; mt < 4; ++mt) {
                f32x4 c = {0.f, 0.f, 0.f, 0.f};
                c = __builtin_amdgcn_mfma_f32_16x16x32_bf16(awin[3 - mt], bfrag[jt][0], c, 0, 0, 0);
                c = __builtin_amdgcn_mfma_f32_16x16x32_bf16(awin[5 - mt], bfrag[jt][1], c, 0, 0, 0);
                if (valid)
                    *(f32x4*)(orow + 16 * mt) = c;   // n = 16mt + 4q .. +3
            }
        }
    }
}

extern "C" void kernel_launch(void* const* d_in, const int* in_sizes, int n_in,
                              void* d_out, int out_size, void* d_ws, size_t ws_size,
                              hipStream_t stream)
{
    const float* in  = (const float*)d_in[0];
    float*       out = (float*)d_out;
    const int batches = in_sizes[0] / (NF * DIM);   // 2048
    holo_fm_kernel<<<dim3(batches), dim3(256), 0, stream>>>(in, out);
}